// Round 5
// baseline (102.885 us; speedup 1.0000x reference)
//
#include <hip/hip_runtime.h>

#define M 32                        // reflection coeffs
#define NC 33                       // floats per row
#define TPB 128                     // threads (rows) per tile
#define FPB (TPB * NC)              // 4224 floats per tile
#define V4 8                        // float4 rounds per thread (4096 floats)
#define TAIL (V4 * 4 * TPB)         // 4096: scalar tail base
#define NBLOCKS 2048                // persistent grid: 8 blocks/CU

typedef float f4 __attribute__((ext_vector_type(4)));

// Levinson step-down for one row staged at lds[rb .. rb+32].
__device__ __forceinline__ void levinson(float* __restrict__ lds, int rb) {
    float ar[M];
#pragma unroll
    for (int j = 0; j < M; ++j) ar[j] = lds[rb + 1 + j];   // GAMMA == 1.0
#pragma unroll
    for (int m = M - 1; m >= 1; --m) {
        float km = ar[m];
        lds[rb + m + 1] = km;
        float z = 1.0f - km * km;
        float r = 1.0f / z;          // exact IEEE div — numerics-critical (R2 lesson)
        const int h = m >> 1;
#pragma unroll
        for (int j = 0; j < h; ++j) {
            float x = ar[j], y = ar[m - 1 - j];
            ar[j]         = (x - km * y) * r;
            ar[m - 1 - j] = (y - km * x) * r;
        }
        if (m & 1) ar[h] = (ar[h] - km * ar[h]) * r;
    }
    lds[rb + 1] = ar[0];
}

__device__ __forceinline__ void store_tile_nt(float* __restrict__ dst,
                                              const float* __restrict__ lds, int t) {
    const f4* l4 = (const f4*)lds;
#pragma unroll
    for (int k = 0; k < V4; ++k) {
        f4 v = l4[t + k * TPB];
        __builtin_nontemporal_store(v, (f4*)dst + t + k * TPB);
    }
    __builtin_nontemporal_store(lds[TAIL + t], dst + TAIL + t);
}

// guarded slow path for a (possibly partial) tile
__device__ __forceinline__ void process_tile_guarded(float* __restrict__ lds,
                                                     const float* __restrict__ a,
                                                     float* __restrict__ out,
                                                     long long base, long long limit, int t) {
    for (int k = 0; k < NC; ++k) {
        int g = t + k * TPB;
        long long ga = base + g;
        lds[g] = (ga < limit) ? a[ga] : 0.0f;
    }
    __syncthreads();
    levinson(lds, t * NC);
    __syncthreads();
    for (int k = 0; k < NC; ++k) {
        int g = t + k * TPB;
        long long ga = base + g;
        if (ga < limit) out[ga] = lds[g];
    }
    __syncthreads();
}

__global__ __launch_bounds__(TPB)
void lpc_to_parcor_kernel(const float* __restrict__ a,
                          float* __restrict__ out,
                          long long nrows, long long tiles_per_block) {
    __shared__ float lds[FPB];
    const int t = threadIdx.x;
    const long long limit = nrows * NC;
    const long long ntiles = (nrows + TPB - 1) / TPB;   // total tiles (last may be partial)
    const long long nfull  = nrows / TPB;               // fully-populated tiles

    long long t0 = (long long)blockIdx.x * tiles_per_block;
    long long t1 = t0 + tiles_per_block; if (t1 > ntiles) t1 = ntiles;
    if (t0 >= t1) return;
    long long fend = (t1 < nfull) ? t1 : nfull;         // full tiles in [t0, fend)

    if (t0 < fend) {
        // ---- prologue: tile t0 -> regs ----
        f4 p[V4]; float pt;
        {
            const float* src = a + t0 * FPB;
            const f4* s4 = (const f4*)src;
#pragma unroll
            for (int k = 0; k < V4; ++k) p[k] = s4[t + k * TPB];
            pt = src[TAIL + t];
        }
        // ---- steady-state pipeline ----
        for (long long ti = t0; ti < fend; ++ti) {
            // regs -> LDS. Per-thread addresses identical to the preceding
            // store-phase ds_reads, so same-wave DS ordering needs no barrier.
            {
                f4* l4 = (f4*)lds;
#pragma unroll
                for (int k = 0; k < V4; ++k) l4[t + k * TPB] = p[k];
                lds[TAIL + t] = pt;
            }
            __syncthreads();

            // issue next tile's global loads; latency hides under levinson
            if (ti + 1 < fend) {
                const float* src = a + (ti + 1) * FPB;
                const f4* s4 = (const f4*)src;
#pragma unroll
                for (int k = 0; k < V4; ++k) p[k] = s4[t + k * TPB];
                pt = src[TAIL + t];
            }
            __builtin_amdgcn_sched_barrier(0);

            levinson(lds, t * NC);
            __syncthreads();

            store_tile_nt(out + ti * FPB, lds, t);
        }
    }
    // ---- guarded tail tiles ----
    for (long long ti = (t0 > nfull ? t0 : nfull); ti < t1; ++ti) {
        __syncthreads();
        process_tile_guarded(lds, a, out, ti * FPB, limit, t);
    }
}

extern "C" void kernel_launch(void* const* d_in, const int* in_sizes, int n_in,
                              void* d_out, int out_size, void* d_ws, size_t ws_size,
                              hipStream_t stream) {
    const float* a = (const float*)d_in[0];
    float* out = (float*)d_out;
    long long nrows = (long long)in_sizes[0] / NC;
    long long ntiles = (nrows + TPB - 1) / TPB;
    long long blocks = (ntiles < NBLOCKS) ? ntiles : NBLOCKS;
    long long tpb_tiles = (ntiles + blocks - 1) / blocks;
    lpc_to_parcor_kernel<<<(int)blocks, TPB, 0, stream>>>(a, out, nrows, tpb_tiles);
}